// Round 14
// baseline (126.278 us; speedup 1.0000x reference)
//
#include <hip/hip_runtime.h>
#include <hip/hip_bf16.h>
#include <stdint.h>

#define P    300
#define HID  128
#define NG   1000
#define HR   160         // half-block rows: 154 valid (150 owned + 2+2 halo) + 6 pad

typedef __attribute__((ext_vector_type(8))) short bf16x8;
typedef __attribute__((ext_vector_type(4))) float f32x4;

// Swizzled bf16 W^T, NATURAL feature order both layers (1-ft/wave).
// chunk(fkey,kc) at fkey*16+(kc^(fkey&15)).
__device__ short g_wsw[2 * HID * HID];
__device__ float g_pool[NG * 2 * HID];   // [graph][half][feature] pooled partials

__device__ __forceinline__ short f2bf(float f) {
    union { float f; uint32_t u; } v; v.f = f;
    uint32_t r = v.u + 0x7fffu + ((v.u >> 16) & 1u);   // RNE
    return (short)(r >> 16);
}
__device__ __forceinline__ uint32_t pkbf2(float a, float b) {   // low=a, high=b
    union { __hip_bfloat162 h; uint32_t u; } cv;
    cv.h = __float22bfloat162_rn(float2{a, b});
    return cv.u;
}

__global__ __launch_bounds__(256) void k_prep(const float* __restrict__ W2,
                                              const float* __restrict__ W3) {
    int b = blockIdx.x;                       // 16 blocks
    const float* W = (b < 8) ? W2 : W3;
    short* dst = g_wsw + ((b < 8) ? 0 : HID * HID);
    int t    = (b & 7) * 256 + threadIdx.x;   // 0..2047 chunks
    int fkey = t >> 4;
    int kc   = t & 15;
    bf16x8 o;
    #pragma unroll
    for (int j = 0; j < 8; ++j)
        o[j] = f2bf(W[(kc * 8 + j) * HID + fkey]);
    *(bf16x8*)&dst[(fkey * 16 + (kc ^ (fkey & 15))) * 8] = o;
}

// ring-average + bias + relu over 4 consecutive node-rows (f32 in regs)
__device__ __forceinline__ void avg_epi(const f32x4 &G, float vp0, float vn3,
                                        float b, float* o) {
    o[0] = (vp0  + G[0] + G[1]) * (1.0f / 3.0f) + b;
    o[1] = (G[0] + G[1] + G[2]) * (1.0f / 3.0f) + b;
    o[2] = (G[1] + G[2] + G[3]) * (1.0f / 3.0f) + b;
    o[3] = (G[2] + G[3] + vn3 ) * (1.0f / 3.0f) + b;
    #pragma unroll
    for (int i = 0; i < 4; ++i) o[i] = o[i] > 0.f ? o[i] : 0.f;
}

// One GCN layer over a HALF-RING (path, no wrap) of 10 tiles; 8 waves,
// wave wv owns ft-tile wv (fkey = wv*16+lm). Rationale (r13 post-mortem):
// the binding resource all session was LDS/graph (77.8 KB -> 2 graphs/CU).
// Half-blocks (41 KB) give 3 blocks/CU = 1.5 graphs in flight (+50%) and
// 6 waves/SIMD. Halo rows are duplicate-computed (+2.7% MFMA); NO wrap
// special-cases remain (ring wrap lives in the x-staging mod).
// 3-PHASE / 2-BARRIER schedule (r4/r13-proven race-free, path version):
//   A: MFMA tiles 5..9 -> GH; barrier
//   B: i=0..4: MFMA tile 4-i -> GL[i]; epi/store tiles 5..9
//      (reads {4..0} vs stores {5..9}: DISJOINT); barrier
//   C: epi/store tiles 0..4
// Row-validity masks [LO,HI] (compile-time): pass0 [1,152], pass1 [2,151].
// Rows outside are neither stored nor pooled; their garbage neighbors
// (tile9 vC, tile0 c15) only feed masked rows. All valid rows' inputs are
// fresh: pass0 needs h1 rows 0..153 (layer-1 computes 0..153, pads 0);
// pass1 needs h2 rows 1..152 (= pass0's store range).
template<int POOL, int LO, int HI>
__device__ __forceinline__ void run_pass(short* __restrict__ buf,
                                         const short* __restrict__ wbase,
                                         const float* __restrict__ bias,
                                         float* __restrict__ pool, int tid) {
    const int lane = tid & 63, wv = tid >> 6, q = lane >> 4, lm = lane & 15;
    const int fkey = wv * 16 + lm;            // this lane's feature
    bf16x8 wf[4];
    #pragma unroll
    for (int kk = 0; kk < 4; ++kk)
        wf[kk] = *(const bf16x8*)&wbase[(fkey * 16 + ((4 * kk + q) ^ lm)) * 8];
    const float biaf = bias[fkey];
    const int kcs = fkey >> 3, offs = fkey & 7;
    const int sA = (q == 0) ? (48 + lm) : (lane - 16);  // r15 carry / row above
    const int sB = (lane + 16) & 63;                    // row below (q<3)

    float psum = 0.f;

    auto mfma_tile = [&](int t, f32x4 &G) {
        const short* tb = buf + t * 2048;
        G = f32x4{0.f, 0.f, 0.f, 0.f};
        #pragma unroll
        for (int kk = 0; kk < 4; ++kk) {
            bf16x8 af = *(const bf16x8*)&tb[(lm * 16 + ((4 * kk + q) ^ lm)) * 8];
            G = __builtin_amdgcn_mfma_f32_16x16x32_bf16(af, wf[kk], G, 0, 0, 0);
        }
    };
    auto store_rows = [&](int T, float (&o)[4]) {
        uint32_t u01 = pkbf2(o[0], o[1]);
        uint32_t u23 = pkbf2(o[2], o[3]);
        int r0 = T * 16 + q * 4;
        if (r0     >= LO && r0     <= HI)
            buf[(r0 * 16       + (kcs ^ ( r0      & 15))) * 8 + offs] = (short)u01;
        if (r0 + 1 >= LO && r0 + 1 <= HI)
            buf[((r0 + 1) * 16 + (kcs ^ ((r0 + 1) & 15))) * 8 + offs] = (short)(u01 >> 16);
        if (r0 + 2 >= LO && r0 + 2 <= HI)
            buf[((r0 + 2) * 16 + (kcs ^ ((r0 + 2) & 15))) * 8 + offs] = (short)u23;
        if (r0 + 3 >= LO && r0 + 3 <= HI)
            buf[((r0 + 3) * 16 + (kcs ^ ((r0 + 3) & 15))) * 8 + offs] = (short)(u23 >> 16);
    };
    auto accum = [&](int T, float (&o)[4]) {
        int r0 = T * 16 + q * 4;
        #pragma unroll
        for (int i = 0; i < 4; ++i)
            if (r0 + i >= LO && r0 + i <= HI) psum += o[i];
    };

    float c15 = 0.f;
    // path epilogue of tile with centers E; N0 = next tile's G[0]
    auto epi_mid = [&](const f32x4 &E, float N0, float (&o)[4]) {
        float vA = __shfl(E[3], sA, 64);
        float vB = __shfl(E[0], sB, 64);
        float vC = __shfl(N0, lm, 64);
        float vp0 = (q == 0) ? c15 : vA;
        float vn3 = (q == 3) ? vC : vB;
        avg_epi(E, vp0, vn3, biaf, o);
        c15 = vA;                 // this tile's r15 -> next tile's vp0(q==0)
    };

    f32x4 GH[5];   // GH[k] = G[5+k]
    f32x4 GL[5];   // GL[i] = G[4-i]

    // ---- phase A: MFMA tiles 5..9 (reads only) ----
    #pragma unroll
    for (int k = 0; k < 5; ++k) mfma_tile(5 + k, GH[k]);
    if (!POOL) __syncthreads();

    // ---- phase B: MFMA 4..0 interleaved with epi/store of 5..9 ----
    #pragma unroll
    for (int i = 0; i < 5; ++i) {
        mfma_tile(4 - i, GL[i]);
        if (i == 0) c15 = __shfl(GL[0][3], 48 + lm, 64);   // tile4 r15 (row 79)
        float o[4];
        float N0 = (i < 4) ? GH[i + 1][0] : GH[4][0];      // i==4: masked rows
        epi_mid(GH[i], N0, o);
        if (POOL) accum(5 + i, o); else store_rows(5 + i, o);
    }
    if (!POOL) __syncthreads();

    // ---- phase C: epi/store tiles 0..4 (stores only) ----
    c15 = 0.f;                                // tile0 row0 < LO in both passes
    #pragma unroll
    for (int k = 0; k < 5; ++k) {
        float o[4];
        float N0 = (k < 4) ? GL[3 - k][0] : GH[0][0];
        epi_mid(GL[4 - k], N0, o);
        if (POOL) accum(k, o); else store_rows(k, o);
    }

    if (POOL) {
        psum += __shfl_xor(psum, 16, 64);
        psum += __shfl_xor(psum, 32, 64);
        if (q == 0) pool[fkey] = psum;
    }
}

// One block (512 thr, 8 waves) per HALF-graph. LDS ~42.2 KB -> 3 blocks/CU
// (126.7 KB < usable ~160 KB) = 24 waves/CU = 6 waves/SIMD, 1.5 graphs in
// flight per CU. Register budget at 6 waves/SIMD: <= 341/wave (m69 pool
// 2048/SIMD); live set ~85. (512,2) caps arch at 128 (r2/r13-verified).
__global__ __launch_bounds__(512, 2) void k_graph(
        const float* __restrict__ x,
        const float* __restrict__ W1,  const float* __restrict__ b1,
        const float* __restrict__ b2v, const float* __restrict__ b3v) {
    __shared__ __align__(16) short buf[HR * HID];   // 40960 B, chunk-swizzled
    __shared__ __align__(16) float xs[316];         // 1264 B
    const int bid = blockIdx.x, g = bid >> 1, half = bid & 1;
    const int tid = threadIdx.x;
    const int start = half * 150;

    // stage x for nodes (start-3 .. start+152) mod 300: xs[j] <-> start-3+j
    if (tid < 156) {
        int gn = start - 3 + tid;
        gn += (gn < 0) ? P : 0;
        gn -= (gn >= P) ? P : 0;
        *(float2*)&xs[2 * tid] = *(const float2*)&x[g * 600 + gn * 2];
    }
    __syncthreads();

    // ---- layer 1: h1[lr] = relu(avg3(x)@W1+b1), lr 0..153; 154..159 zero ----
    // h1 row lr <-> node start-2+lr; avg3 = xs rows lr, lr+1, lr+2.
    {
        const int kc1 = tid & 15;
        const int n0  = tid >> 4;            // 0..31
        float w1x[8], w1y[8], b1v[8];
        #pragma unroll
        for (int j = 0; j < 8; ++j) {
            w1x[j] = W1[kc1 * 8 + j];
            w1y[j] = W1[HID + kc1 * 8 + j];
            b1v[j] = b1[kc1 * 8 + j];
        }
        #pragma unroll
        for (int it = 0; it < 5; ++it) {
            int row = it * 32 + n0;          // 0..159
            uint32_t w[4] = {0u, 0u, 0u, 0u};
            if (row < 154) {
                float2 xp = *(const float2*)&xs[2 * row];
                float2 xc = *(const float2*)&xs[2 * row + 2];
                float2 xn = *(const float2*)&xs[2 * row + 4];
                float ax = (xp.x + xc.x + xn.x) * (1.f / 3.f);
                float ay = (xp.y + xc.y + xn.y) * (1.f / 3.f);
                #pragma unroll
                for (int jj = 0; jj < 4; ++jj) {
                    float va = ax * w1x[2*jj]   + ay * w1y[2*jj]   + b1v[2*jj];
                    float vb = ax * w1x[2*jj+1] + ay * w1y[2*jj+1] + b1v[2*jj+1];
                    va = va > 0.f ? va : 0.f;
                    vb = vb > 0.f ? vb : 0.f;
                    w[jj] = pkbf2(va, vb);
                }
            }
            *(uint4*)&buf[(row * 16 + (kc1 ^ (row & 15))) * 8] =
                uint4{w[0], w[1], w[2], w[3]};
        }
    }
    __syncthreads();

    run_pass<0, 1, 152>(buf, g_wsw,             b2v, nullptr, tid);
    __syncthreads();
    run_pass<1, 2, 151>(buf, g_wsw + HID * HID, b3v,
                        &g_pool[(g * 2 + half) * HID], tid);
}

// pool-merge + FC head; kernel boundary = coherence for g_pool.
__global__ __launch_bounds__(128) void k_fc(
        const float* __restrict__ fw1, const float* __restrict__ fb1,
        const float* __restrict__ fw2, const float* __restrict__ fb2,
        float* __restrict__ out) {
    __shared__ float pl[128], s1[128];
    const int g = blockIdx.x, f = threadIdx.x;
    pl[f] = g_pool[g * 256 + f] + g_pool[g * 256 + 128 + f];
    __syncthreads();
    float p = 0.f;
    const float* c = fw1 + f;
    #pragma unroll 8
    for (int k = 0; k < 128; ++k) p += pl[k] * c[k * 128];
    float o1 = fb1[f] + p * (1.0f / 300.0f);
    s1[f] = o1 > 0.f ? o1 : 0.f;
    __syncthreads();
    int o = f >> 6, ln = f & 63;
    float v = s1[ln] * fw2[ln * 2 + o] + s1[ln + 64] * fw2[(ln + 64) * 2 + o];
    #pragma unroll
    for (int off = 1; off <= 32; off <<= 1)
        v += __shfl_xor(v, off, 64);
    if (ln == 0) out[g * 2 + o] = v + fb2[o];
}

extern "C" void kernel_launch(void* const* d_in, const int* in_sizes, int n_in,
                              void* d_out, int out_size, void* d_ws, size_t ws_size,
                              hipStream_t stream) {
    const float* x   = (const float*)d_in[0];
    const float* W1  = (const float*)d_in[3];
    const float* b1  = (const float*)d_in[4];
    const float* W2  = (const float*)d_in[5];
    const float* b2  = (const float*)d_in[6];
    const float* W3  = (const float*)d_in[7];
    const float* b3  = (const float*)d_in[8];
    const float* fw1 = (const float*)d_in[9];
    const float* fb1 = (const float*)d_in[10];
    const float* fw2 = (const float*)d_in[11];
    const float* fb2 = (const float*)d_in[12];
    float* out = (float*)d_out;

    k_prep <<<dim3(16),     dim3(256), 0, stream>>>(W2, W3);
    k_graph<<<dim3(2 * NG), dim3(512), 0, stream>>>(x, W1, b1, b2, b3);
    k_fc   <<<dim3(NG),     dim3(128), 0, stream>>>(fw1, fb1, fw2, fb2, out);
}